// Round 1
// baseline (53.634 us; speedup 1.0000x reference)
//
#include <hip/hip_runtime.h>

#define EPSILON_F 5.0f

// Pass 1: wave-per-row hinge loss, block partial sums -> d_ws.
// grid = 2048 blocks x 256 threads = 8192 waves; B/8192 = 32 rows per wave.
__global__ __launch_bounds__(256) void ncl_partial_kernel(
    const float* __restrict__ feat,     // [B, 256]
    const float* __restrict__ means,    // [C, 256]
    const int* __restrict__ labels,     // [B]
    float* __restrict__ partials,       // [gridDim.x]
    int B)
{
    const int lane = threadIdx.x & 63;
    const int wave = threadIdx.x >> 6;
    const int waves_per_block = blockDim.x >> 6;
    const int gwave = blockIdx.x * waves_per_block + wave;
    const int nwaves = gridDim.x * waves_per_block;

    float acc = 0.0f;
    for (int r = gwave; r < B; r += nwaves) {
        const float4 f = *reinterpret_cast<const float4*>(feat + (size_t)r * 256 + lane * 4);
        const int lab = labels[r];  // wave-uniform -> broadcast load
        const float4 m = *reinterpret_cast<const float4*>(means + (size_t)lab * 256 + lane * 4);
        const float dx = f.x - m.x;
        const float dy = f.y - m.y;
        const float dz = f.z - m.z;
        const float dw = f.w - m.w;
        float d2 = dx * dx + dy * dy + dz * dz + dw * dw;
        // 64-lane butterfly: all lanes end with the full row sum
        #pragma unroll
        for (int off = 32; off; off >>= 1) d2 += __shfl_xor(d2, off, 64);
        if (lane == 0) acc += fmaxf(EPSILON_F - sqrtf(d2), 0.0f);
    }

    __shared__ float wsum[8];
    if (lane == 0) wsum[wave] = acc;
    __syncthreads();
    if (threadIdx.x == 0) {
        float s = 0.0f;
        for (int w = 0; w < waves_per_block; ++w) s += wsum[w];
        partials[blockIdx.x] = s;
    }
}

// Pass 2: deterministic reduce of block partials -> mean.
__global__ __launch_bounds__(256) void ncl_final_kernel(
    const float* __restrict__ partials, int n, float* __restrict__ out, float invB)
{
    float s = 0.0f;
    for (int i = threadIdx.x; i < n; i += 256) s += partials[i];
    #pragma unroll
    for (int off = 32; off; off >>= 1) s += __shfl_xor(s, off, 64);
    __shared__ float wsum[4];
    if ((threadIdx.x & 63) == 0) wsum[threadIdx.x >> 6] = s;
    __syncthreads();
    if (threadIdx.x == 0) out[0] = (wsum[0] + wsum[1] + wsum[2] + wsum[3]) * invB;
}

extern "C" void kernel_launch(void* const* d_in, const int* in_sizes, int n_in,
                              void* d_out, int out_size, void* d_ws, size_t ws_size,
                              hipStream_t stream)
{
    const float* feat   = (const float*)d_in[0];   // [B, 256] f32
    const float* means  = (const float*)d_in[1];   // [C, 256] f32
    const int*   labels = (const int*)d_in[2];     // [B] int
    float* out = (float*)d_out;

    const int B = in_sizes[0] / 256;
    const int NBLOCKS = 2048;
    float* partials = (float*)d_ws;  // 2048 floats = 8 KB of scratch

    ncl_partial_kernel<<<NBLOCKS, 256, 0, stream>>>(feat, means, labels, partials, B);
    ncl_final_kernel<<<1, 256, 0, stream>>>(partials, NBLOCKS, out, 1.0f / (float)B);
}

// Round 2
// 49.027 us; speedup vs baseline: 1.0940x; 1.0940x over previous
//
#include <hip/hip_runtime.h>

#define EPSILON_F 5.0f

// Pass 1: each wave processes chunks of 4 consecutive rows.
//  - one 16B broadcast int4 load fetches 4 labels
//  - 4 feat float4 loads + 4 means float4 loads issued back-to-back (deep MLP)
//  - 4 independent 6-step butterflies (DS-pipe latency overlapped)
// grid = 2048 blocks x 256 threads = 8192 waves; nchunks = B/4 = 65536 -> 8 chunks/wave.
__global__ __launch_bounds__(256) void ncl_partial_kernel(
    const float* __restrict__ feat,     // [B, 256]
    const float* __restrict__ means,    // [C, 256]
    const int* __restrict__ labels,     // [B]
    float* __restrict__ partials,       // [gridDim.x]
    int nchunks)                        // B / 4
{
    const int lane = threadIdx.x & 63;
    const int wave = threadIdx.x >> 6;
    const int gwave = blockIdx.x * (blockDim.x >> 6) + wave;
    const int nwaves = gridDim.x * (blockDim.x >> 6);

    float acc = 0.0f;
    for (int c = gwave; c < nchunks; c += nwaves) {
        const size_t rb = (size_t)c * 4;  // first row of this 4-row chunk
        // 4 labels in one wave-uniform 16B load (broadcast, 1 transaction)
        const int4 lv = *reinterpret_cast<const int4*>(labels + rb);

        const float* fp = feat + rb * 256 + lane * 4;
        const float4 f0 = *reinterpret_cast<const float4*>(fp);
        const float4 f1 = *reinterpret_cast<const float4*>(fp + 256);
        const float4 f2 = *reinterpret_cast<const float4*>(fp + 512);
        const float4 f3 = *reinterpret_cast<const float4*>(fp + 768);

        const float4 m0 = *reinterpret_cast<const float4*>(means + (size_t)lv.x * 256 + lane * 4);
        const float4 m1 = *reinterpret_cast<const float4*>(means + (size_t)lv.y * 256 + lane * 4);
        const float4 m2 = *reinterpret_cast<const float4*>(means + (size_t)lv.z * 256 + lane * 4);
        const float4 m3 = *reinterpret_cast<const float4*>(means + (size_t)lv.w * 256 + lane * 4);

        float d0, d1, d2, d3;
        { float x=f0.x-m0.x, y=f0.y-m0.y, z=f0.z-m0.z, w=f0.w-m0.w; d0 = x*x + y*y + z*z + w*w; }
        { float x=f1.x-m1.x, y=f1.y-m1.y, z=f1.z-m1.z, w=f1.w-m1.w; d1 = x*x + y*y + z*z + w*w; }
        { float x=f2.x-m2.x, y=f2.y-m2.y, z=f2.z-m2.z, w=f2.w-m2.w; d2 = x*x + y*y + z*z + w*w; }
        { float x=f3.x-m3.x, y=f3.y-m3.y, z=f3.z-m3.z, w=f3.w-m3.w; d3 = x*x + y*y + z*z + w*w; }

        // 4 independent butterflies -> pipelined on the DS/permute path
        #pragma unroll
        for (int off = 32; off; off >>= 1) {
            d0 += __shfl_xor(d0, off, 64);
            d1 += __shfl_xor(d1, off, 64);
            d2 += __shfl_xor(d2, off, 64);
            d3 += __shfl_xor(d3, off, 64);
        }

        // all lanes hold identical row sums -> no divergence
        acc += fmaxf(EPSILON_F - sqrtf(d0), 0.0f)
             + fmaxf(EPSILON_F - sqrtf(d1), 0.0f)
             + fmaxf(EPSILON_F - sqrtf(d2), 0.0f)
             + fmaxf(EPSILON_F - sqrtf(d3), 0.0f);
    }

    // acc is wave-uniform; combine the block's 4 waves
    __shared__ float wsum[4];
    if (lane == 0) wsum[wave] = acc;
    __syncthreads();
    if (threadIdx.x == 0)
        partials[blockIdx.x] = wsum[0] + wsum[1] + wsum[2] + wsum[3];
}

// Pass 2: deterministic reduce of block partials -> mean.
__global__ __launch_bounds__(256) void ncl_final_kernel(
    const float* __restrict__ partials, int n, float* __restrict__ out, float invB)
{
    float s = 0.0f;
    for (int i = threadIdx.x; i < n; i += 256) s += partials[i];
    #pragma unroll
    for (int off = 32; off; off >>= 1) s += __shfl_xor(s, off, 64);
    __shared__ float wsum[4];
    if ((threadIdx.x & 63) == 0) wsum[threadIdx.x >> 6] = s;
    __syncthreads();
    if (threadIdx.x == 0) out[0] = (wsum[0] + wsum[1] + wsum[2] + wsum[3]) * invB;
}

extern "C" void kernel_launch(void* const* d_in, const int* in_sizes, int n_in,
                              void* d_out, int out_size, void* d_ws, size_t ws_size,
                              hipStream_t stream)
{
    const float* feat   = (const float*)d_in[0];   // [B, 256] f32
    const float* means  = (const float*)d_in[1];   // [C, 256] f32
    const int*   labels = (const int*)d_in[2];     // [B] int
    float* out = (float*)d_out;

    const int B = in_sizes[0] / 256;
    const int NBLOCKS = 2048;
    float* partials = (float*)d_ws;  // 2048 floats = 8 KB scratch

    ncl_partial_kernel<<<NBLOCKS, 256, 0, stream>>>(feat, means, labels, partials, B / 4);
    ncl_final_kernel<<<1, 256, 0, stream>>>(partials, NBLOCKS, out, 1.0f / (float)B);
}